// Round 5
// baseline (368.009 us; speedup 1.0000x reference)
//
#include <hip/hip_runtime.h>
#include <hip/hip_cooperative_groups.h>

namespace cg = cooperative_groups;

#define NTOT 65536   // B * NPG
#define DIM  512
#define BGR  64
#define NPG  1024
#define DROPN 512    // NPG - ceil(0.5 * NPG)
#define SLICES 4     // edge slices per graph (NBLK / BGR)
#define NBLK 256     // one block per CU -> cooperative co-residency guaranteed
#define NTHR 1024

typedef float vf4 __attribute__((ext_vector_type(4)));
typedef unsigned long long u64;

__global__ __launch_bounds__(NTHR, 4) void fused_all(
        const float* __restrict__ X, const float* __restrict__ W,
        const int* __restrict__ src, const int* __restrict__ dst,
        const float* __restrict__ bias,
        float* __restrict__ p, float* __restrict__ norm,
        int* __restrict__ deg_part, float* __restrict__ agg_part,
        float* __restrict__ gate, float* __restrict__ out, int epg) {
    cg::grid_group grid = cg::this_grid();
    __shared__ u64 smem64[NPG];                 // 8 KB, aliased per phase

    const int t       = threadIdx.x;
    const int lane    = t & 63;
    const int gw      = blockIdx.x * (NTHR / 64) + (t >> 6);   // global wave id
    const int NW      = NBLK * (NTHR / 64);                    // 4096 waves
    const int g       = blockIdx.x & (BGR - 1);
    const int slice   = blockIdx.x >> 6;                       // 0..SLICES-1
    const int nbase   = g * NPG;
    const int eps     = epg / SLICES;

    // ================= Phase A1: p = X @ W (wave-per-row) =================
    {
        const vf4* wr = (const vf4*)W;
        const vf4 w0 = wr[lane], w1 = wr[lane + 64];
        for (int row = gw; row < NTOT; row += 2 * NW) {
            const int row2 = row + NW;                         // NTOT % (2*NW) == 0
            const vf4* xr0 = (const vf4*)(X + (size_t)row  * DIM);
            const vf4* xr1 = (const vf4*)(X + (size_t)row2 * DIM);
            vf4 a0 = xr0[lane], a1 = xr0[lane + 64];
            vf4 b0 = xr1[lane], b1 = xr1[lane + 64];
            vf4 m0 = a0 * w0 + a1 * w1;
            vf4 m1 = b0 * w0 + b1 * w1;
            float s0 = m0[0] + m0[1] + m0[2] + m0[3];
            float s1 = m1[0] + m1[1] + m1[2] + m1[3];
            #pragma unroll
            for (int off = 32; off > 0; off >>= 1) {
                s0 += __shfl_down(s0, off, 64);
                s1 += __shfl_down(s1, off, 64);
            }
            if (lane == 0) { p[row] = s0; p[row2] = s1; }
        }
    }

    // ========== Phase A2: per-(graph,slice) in-degree LDS histogram ==========
    {
        int* dl = (int*)smem64;
        for (int i = t; i < NPG; i += NTHR) dl[i] = 0;
        __syncthreads();
        const int4* d4 = (const int4*)(dst + (size_t)g * epg + (size_t)slice * eps);
        const int n4 = eps >> 2;
        for (int i = t; i < n4; i += NTHR) {
            int4 d = d4[i];
            atomicAdd(&dl[d.x - nbase], 1);
            atomicAdd(&dl[d.y - nbase], 1);
            atomicAdd(&dl[d.z - nbase], 1);
            atomicAdd(&dl[d.w - nbase], 1);
        }
        __syncthreads();
        int* op = deg_part + (size_t)slice * NTOT + nbase;
        for (int i = t; i < NPG; i += NTHR) op[i] = dl[i];
    }
    grid.sync();

    // ===== Phase B: norm + hn staged in LDS; LDS scatter-sum; agg partial =====
    {
        float* hl = (float*)smem64;                 // [NPG]
        float* al = ((float*)smem64) + NPG;         // [NPG]
        for (int i = t; i < NPG; i += NTHR) {
            int d = 0;
            #pragma unroll
            for (int s = 0; s < SLICES; s++) d += deg_part[(size_t)s * NTOT + nbase + i];
            float nr = d > 0 ? (1.0f / sqrtf((float)d)) : 0.f;
            hl[i] = p[nbase + i] * nr;
            al[i] = 0.f;
            if (slice == 0) norm[nbase + i] = nr;
        }
        __syncthreads();
        const int4* s4 = (const int4*)(src + (size_t)g * epg + (size_t)slice * eps);
        const int4* d4 = (const int4*)(dst + (size_t)g * epg + (size_t)slice * eps);
        const int n4 = eps >> 2;
        for (int i = t; i < n4; i += NTHR) {
            int4 s = s4[i];
            int4 d = d4[i];
            atomicAdd(&al[d.x - nbase], hl[s.x - nbase]);
            atomicAdd(&al[d.y - nbase], hl[s.y - nbase]);
            atomicAdd(&al[d.z - nbase], hl[s.z - nbase]);
            atomicAdd(&al[d.w - nbase], hl[s.w - nbase]);
        }
        __syncthreads();
        float* op = agg_part + (size_t)slice * NTOT + nbase;
        for (int i = t; i < NPG; i += NTHR) op[i] = al[i];
    }
    grid.sync();

    // ====== Phase C: blocks 0..63: score + stable hybrid bitonic top-k ======
    if (blockIdx.x < BGR) {
        u64* sk = smem64;
        const int nb2 = blockIdx.x * NPG;
        float a = 0.f;
        #pragma unroll
        for (int s = 0; s < SLICES; s++) a += agg_part[(size_t)s * NTOT + nb2 + t];
        float w = a * norm[nb2 + t] + bias[0];
        w = w > 0.f ? w : 0.f;             // relu; w>=0 -> float bits order-preserving
        u64 key = ((u64)__float_as_uint(w) << 32) | (unsigned int)t;
        // ascending bitonic sort of 1024 unique (value,index) keys == stable argsort
        for (int k = 2; k <= NPG; k <<= 1) {
            const bool up = ((t & k) == 0);
            for (int j = k >> 1; j >= 64; j >>= 1) {          // cross-wave via LDS
                sk[t] = key;
                __syncthreads();
                u64 partner = sk[t ^ j];
                __syncthreads();
                bool takeMin = (((t & j) == 0) == up);
                key = takeMin ? (key < partner ? key : partner)
                              : (key > partner ? key : partner);
            }
            for (int j = ((k >> 1) < 32 ? (k >> 1) : 32); j >= 1; j >>= 1) {  // in-wave
                u64 partner = (u64)__shfl_xor((long long)key, j, 64);
                bool takeMin = (((t & j) == 0) == up);
                key = takeMin ? (key < partner ? key : partner)
                              : (key > partner ? key : partner);
            }
        }
        int idx = (int)(key & 0xffffffffull);
        float wv = __uint_as_float((unsigned int)(key >> 32));
        gate[nb2 + idx] = (t < DROPN) ? 0.f : wv;
    }
    grid.sync();

    // ============ Phase D: out[row,:] = X[row,:] * gate[row] ============
    for (int row = gw; row < NTOT; row += NW) {
        float gv = gate[row];
        vf4* o = (vf4*)(out + (size_t)row * DIM);
        if (gv == 0.f) {                   // wave-uniform (whole wave = one row)
            vf4 z = (vf4){0.f, 0.f, 0.f, 0.f};
            o[lane] = z;
            o[lane + 64] = z;
        } else {
            const vf4* xr = (const vf4*)(X + (size_t)row * DIM);
            o[lane]      = xr[lane] * gv;
            o[lane + 64] = xr[lane + 64] * gv;
        }
    }
}

extern "C" void kernel_launch(void* const* d_in, const int* in_sizes, int n_in,
                              void* d_out, int out_size, void* d_ws, size_t ws_size,
                              hipStream_t stream) {
    const float* X    = (const float*)d_in[0];
    const int*   src  = (const int*)d_in[1];
    const int*   dst  = (const int*)d_in[2];
    const float* W    = (const float*)d_in[3];
    const float* bias = (const float*)d_in[4];
    float* out = (float*)d_out;
    int E   = in_sizes[1];
    int epg = E / BGR;

    float* ws       = (float*)d_ws;
    float* p        = ws;                            // [N] f32
    float* norm     = ws + 1 * NTOT;                 // [N] f32
    float* gate     = ws + 2 * NTOT;                 // [N] f32
    int*   deg_part = (int*)(ws + 3 * NTOT);         // [SLICES][N] i32
    float* agg_part = ws + (3 + SLICES) * NTOT;      // [SLICES][N] f32

    void* args[] = {
        (void*)&X, (void*)&W, (void*)&src, (void*)&dst, (void*)&bias,
        (void*)&p, (void*)&norm, (void*)&deg_part, (void*)&agg_part,
        (void*)&gate, (void*)&out, (void*)&epg
    };
    hipLaunchCooperativeKernel((void*)fused_all, dim3(NBLK), dim3(NTHR),
                               args, 0, stream);
}

// Round 6
// 276.003 us; speedup vs baseline: 1.3334x; 1.3334x over previous
//
#include <hip/hip_runtime.h>

#define NTOT 65536   // B * NPG
#define DIM  512
#define BGR  64
#define NPG  1024
#define DROPN 512    // NPG - ceil(0.5 * NPG)
#define SLICES 8     // edge slices per graph
#define DEG_BLOCKS (BGR * SLICES)   // 512
#define MV_BLOCKS 2048

typedef float vf4 __attribute__((ext_vector_type(4)));
typedef unsigned long long u64;

// ---- K1: blocks [0,512): per-(graph,slice) in-degree partials (LDS histogram);
//      blocks [512,2560): p = X@W wave-per-row ----
__global__ __launch_bounds__(256) void k1_matvec_deg(
        const float* __restrict__ X, const float* __restrict__ W,
        const int* __restrict__ dst,
        float* __restrict__ p, int* __restrict__ deg_part, int epg) {
    __shared__ int dl[NPG];
    if (blockIdx.x < DEG_BLOCKS) {
        const int b = blockIdx.x;                    // 0..511
        const int g = b & (BGR - 1);
        const int slice = b >> 6;
        const int nbase = g * NPG;
        const int eps = epg / SLICES;
        for (int i = threadIdx.x; i < NPG; i += 256) dl[i] = 0;
        __syncthreads();
        const int4* d4 = (const int4*)(dst + (size_t)g * epg + (size_t)slice * eps);
        const int n4 = eps >> 2;
        for (int i = threadIdx.x; i < n4; i += 256) {
            int4 d = d4[i];
            atomicAdd(&dl[d.x - nbase], 1);
            atomicAdd(&dl[d.y - nbase], 1);
            atomicAdd(&dl[d.z - nbase], 1);
            atomicAdd(&dl[d.w - nbase], 1);
        }
        __syncthreads();
        int* op = deg_part + (size_t)slice * NTOT + nbase;
        for (int i = threadIdx.x; i < NPG; i += 256) op[i] = dl[i];
    } else {
        const int lane = threadIdx.x & 63;
        const int wid  = ((blockIdx.x - DEG_BLOCKS) * 256 + threadIdx.x) >> 6; // 0..8191
        const int nw   = (MV_BLOCKS * 256) >> 6;                               // 8192
        const vf4* wr = (const vf4*)W;
        const vf4 w0 = wr[lane], w1 = wr[lane + 64];
        for (int row = wid; row < NTOT; row += 2 * nw) {
            const int row2 = row + nw;                         // NTOT % (2*nw) == 0
            const vf4* xr0 = (const vf4*)(X + (size_t)row  * DIM);
            const vf4* xr1 = (const vf4*)(X + (size_t)row2 * DIM);
            vf4 a0 = xr0[lane], a1 = xr0[lane + 64];
            vf4 b0 = xr1[lane], b1 = xr1[lane + 64];
            vf4 m0 = a0 * w0 + a1 * w1;
            vf4 m1 = b0 * w0 + b1 * w1;
            float s0 = m0[0] + m0[1] + m0[2] + m0[3];
            float s1 = m1[0] + m1[1] + m1[2] + m1[3];
            #pragma unroll
            for (int off = 32; off > 0; off >>= 1) {
                s0 += __shfl_down(s0, off, 64);
                s1 += __shfl_down(s1, off, 64);
            }
            if (lane == 0) { p[row] = s0; p[row2] = s1; }
        }
    }
}

// ---- K2: per (graph,slice): sum deg partials -> norm; hn staged in LDS;
//      LDS scatter-sum of slice edges; write agg partial ----
__global__ __launch_bounds__(256) void k2_agg(
        const int* __restrict__ src, const int* __restrict__ dst,
        const float* __restrict__ p, const int* __restrict__ deg_part,
        float* __restrict__ agg_part, float* __restrict__ norm_out, int epg) {
    __shared__ float hl[NPG];
    __shared__ float al[NPG];
    const int b = blockIdx.x;
    const int g = b & (BGR - 1);
    const int slice = b >> 6;
    const int nbase = g * NPG;
    const int eps = epg / SLICES;
    for (int i = threadIdx.x; i < NPG; i += 256) {
        int d = 0;
        #pragma unroll
        for (int s = 0; s < SLICES; s++) d += deg_part[(size_t)s * NTOT + nbase + i];
        float nrm = d > 0 ? (1.0f / sqrtf((float)d)) : 0.f;
        hl[i] = p[nbase + i] * nrm;
        al[i] = 0.f;
        if (slice == 0) norm_out[nbase + i] = nrm;
    }
    __syncthreads();
    const int4* s4 = (const int4*)(src + (size_t)g * epg + (size_t)slice * eps);
    const int4* d4 = (const int4*)(dst + (size_t)g * epg + (size_t)slice * eps);
    const int n4 = eps >> 2;
    for (int i = threadIdx.x; i < n4; i += 256) {
        int4 s = s4[i];
        int4 d = d4[i];
        atomicAdd(&al[d.x - nbase], hl[s.x - nbase]);
        atomicAdd(&al[d.y - nbase], hl[s.y - nbase]);
        atomicAdd(&al[d.z - nbase], hl[s.z - nbase]);
        atomicAdd(&al[d.w - nbase], hl[s.w - nbase]);
    }
    __syncthreads();
    float* op = agg_part + (size_t)slice * NTOT + nbase;
    for (int i = threadIdx.x; i < NPG; i += 256) op[i] = al[i];
}

// ---- K3: per graph: w = relu(agg*norm + bias); hybrid register bitonic sort ----
__global__ __launch_bounds__(1024) void k3_topk(
        const float* __restrict__ agg_part, const float* __restrict__ norm,
        const float* __restrict__ bias, float* __restrict__ gate) {
    __shared__ u64 sk[NPG];
    const int g = blockIdx.x;
    const int t = threadIdx.x;
    const int nbase = g * NPG;
    float a = 0.f;
    #pragma unroll
    for (int s = 0; s < SLICES; s++) a += agg_part[(size_t)s * NTOT + nbase + t];
    float w = a * norm[nbase + t] + bias[0];
    w = w > 0.f ? w : 0.f;                // relu; w>=0 -> float bits order-preserving
    u64 key = ((u64)__float_as_uint(w) << 32) | (unsigned int)t;
    // ascending bitonic sort of 1024 unique (value,index) keys == jnp stable argsort
    for (int k = 2; k <= NPG; k <<= 1) {
        const bool up = ((t & k) == 0);
        for (int j = k >> 1; j >= 64; j >>= 1) {      // cross-wave: LDS exchange
            sk[t] = key;
            __syncthreads();
            u64 partner = sk[t ^ j];
            __syncthreads();
            bool takeMin = (((t & j) == 0) == up);
            key = takeMin ? (key < partner ? key : partner)
                          : (key > partner ? key : partner);
        }
        for (int j = ((k >> 1) < 32 ? (k >> 1) : 32); j >= 1; j >>= 1) {  // in-wave
            u64 partner = (u64)__shfl_xor((long long)key, j, 64);
            bool takeMin = (((t & j) == 0) == up);
            key = takeMin ? (key < partner ? key : partner)
                          : (key > partner ? key : partner);
        }
    }
    int idx = (int)(key & 0xffffffffull);
    float wv = __uint_as_float((unsigned int)(key >> 32));
    gate[nbase + idx] = (t < DROPN) ? 0.f : wv;
}

// ---- K4: out[row,:] = X[row,:] * gate[row]; NT stores keep X L3-resident ----
__global__ __launch_bounds__(256) void k4_gate(
        const float* __restrict__ X, const float* __restrict__ gate,
        float* __restrict__ out) {
    const int lane = threadIdx.x & 63;
    const int nw   = (gridDim.x * blockDim.x) >> 6;
    const int wid  = (blockIdx.x * blockDim.x + threadIdx.x) >> 6;
    for (int row = wid; row < NTOT; row += nw) {
        float g = gate[row];
        vf4* o = (vf4*)(out + (size_t)row * DIM);
        if (g == 0.f) {                    // wave-uniform (whole wave = one row)
            vf4 z = (vf4){0.f, 0.f, 0.f, 0.f};
            __builtin_nontemporal_store(z, &o[lane]);
            __builtin_nontemporal_store(z, &o[lane + 64]);
        } else {
            const vf4* xr = (const vf4*)(X + (size_t)row * DIM);
            vf4 a = xr[lane] * g;
            vf4 c = xr[lane + 64] * g;
            __builtin_nontemporal_store(a, &o[lane]);
            __builtin_nontemporal_store(c, &o[lane + 64]);
        }
    }
}

extern "C" void kernel_launch(void* const* d_in, const int* in_sizes, int n_in,
                              void* d_out, int out_size, void* d_ws, size_t ws_size,
                              hipStream_t stream) {
    const float* X    = (const float*)d_in[0];
    const int*   src  = (const int*)d_in[1];
    const int*   dst  = (const int*)d_in[2];
    const float* W    = (const float*)d_in[3];
    const float* bias = (const float*)d_in[4];
    float* out = (float*)d_out;
    int E   = in_sizes[1];
    int epg = E / BGR;

    float* ws       = (float*)d_ws;
    float* p        = ws;                       // [N] f32
    float* norm     = ws + 1 * NTOT;            // [N] f32
    float* gate     = ws + 2 * NTOT;            // [N] f32
    int*   deg_part = (int*)(ws + 3 * NTOT);    // [SLICES][N] i32
    float* agg_part = ws + (3 + SLICES) * NTOT; // [SLICES][N] f32

    k1_matvec_deg<<<MV_BLOCKS + DEG_BLOCKS, 256, 0, stream>>>(X, W, dst, p, deg_part, epg);
    k2_agg<<<BGR * SLICES, 256, 0, stream>>>(src, dst, p, deg_part, agg_part, norm, epg);
    k3_topk<<<BGR, 1024, 0, stream>>>(agg_part, norm, bias, gate);
    k4_gate<<<2048, 256, 0, stream>>>(X, gate, out);
}